// Round 1
// baseline (481.791 us; speedup 1.0000x reference)
//
#include <hip/hip_runtime.h>
#include <cstdint>
#include <cstddef>

typedef unsigned short u16;
typedef __bf16 bf16x8 __attribute__((ext_vector_type(8)));
typedef float f32x4 __attribute__((ext_vector_type(4)));
typedef unsigned short u16x4 __attribute__((ext_vector_type(4)));
typedef unsigned short u16x8 __attribute__((ext_vector_type(8)));
typedef __attribute__((address_space(1))) unsigned int as1_uint;
typedef __attribute__((address_space(3))) unsigned int as3_uint;

__device__ __forceinline__ u16 f2bf(float f) {
  uint32_t u = __builtin_bit_cast(uint32_t, f);
  u += 0x7FFFu + ((u >> 16) & 1u);   // RNE to bf16
  return (u16)(u >> 16);
}

__device__ __forceinline__ void gld_lds16(const void* g, void* l) {
  __builtin_amdgcn_global_load_lds((as1_uint*)g, (as3_uint*)l, 16, 0, 0);
}

// ---------------- cast fp32 -> bf16, 8 elems/thread ----------------
__global__ __launch_bounds__(256) void k_cast(const float* __restrict__ in,
                                              u16* __restrict__ out, int n8) {
  int i = blockIdx.x * 256 + threadIdx.x;
  if (i >= n8) return;
  const float4* p = reinterpret_cast<const float4*>(in) + (size_t)i * 2;
  float4 a = p[0], b = p[1];
  u16x8 r;
  r[0] = f2bf(a.x); r[1] = f2bf(a.y); r[2] = f2bf(a.z); r[3] = f2bf(a.w);
  r[4] = f2bf(b.x); r[5] = f2bf(b.y); r[6] = f2bf(b.z); r[7] = f2bf(b.w);
  *reinterpret_cast<u16x8*>(out + (size_t)i * 8) = r;
}

// ---------------- W [K][N] f32  ->  Wt [N][K] bf16 ----------------
__global__ __launch_bounds__(256) void k_transpose_cast(const float* __restrict__ W,
                                                        u16* __restrict__ Wt,
                                                        int K, int N) {
  __shared__ u16 tile[64][72];
  int k0 = blockIdx.y * 64, n0 = blockIdx.x * 64;
  int r = threadIdx.x >> 4;
  int c4 = (threadIdx.x & 15) * 4;
#pragma unroll
  for (int i = 0; i < 4; ++i) {
    int kk = r + i * 16;
    float4 v = *reinterpret_cast<const float4*>(W + (size_t)(k0 + kk) * N + n0 + c4);
    tile[kk][c4 + 0] = f2bf(v.x); tile[kk][c4 + 1] = f2bf(v.y);
    tile[kk][c4 + 2] = f2bf(v.z); tile[kk][c4 + 3] = f2bf(v.w);
  }
  __syncthreads();
#pragma unroll
  for (int i = 0; i < 4; ++i) {
    int nn = r + i * 16;
    u16x4 o;
    o[0] = tile[c4 + 0][nn]; o[1] = tile[c4 + 1][nn];
    o[2] = tile[c4 + 2][nn]; o[3] = tile[c4 + 3][nn];
    *reinterpret_cast<u16x4*>(Wt + (size_t)(n0 + nn) * K + k0 + c4) = o;
  }
}

// ---------------- concat qkv bias ----------------
__global__ __launch_bounds__(256) void k_concat_bias(const float* __restrict__ bq,
                                                     const float* __restrict__ bk,
                                                     const float* __restrict__ bv,
                                                     float* __restrict__ out) {
  int i = blockIdx.x * 256 + threadIdx.x;
  if (i >= 3072) return;
  float v;
  if (i < 2048) v = bq[i];
  else if (i < 2560) v = bk[i - 2048];
  else v = bv[i - 2560];
  out[i] = v;
}

// ---------------- bf16 GEMM: C = A[M][K] @ Bt[N][K]^T + bias ----------------
// 128x128 tile, BK=64, 4 waves (2x2), 16x16x32 MFMA.
// LDS: linear dest for global_load_lds, source chunk pre-swizzled by (l&7)^((l>>3)&7),
// reads apply chunk ^= (row&7)  (both-sides-or-neither, guide rule 21).
template <bool F32OUT>
__global__ __launch_bounds__(256) void k_gemm(const u16* __restrict__ A,
                                              const u16* __restrict__ Bt,
                                              const float* __restrict__ bias,
                                              void* __restrict__ Cout,
                                              int M, int N, int K) {
  __shared__ __align__(16) u16 As[128 * 64];
  __shared__ __align__(16) u16 Bs[128 * 64];
  const int m0 = blockIdx.y * 128, n0 = blockIdx.x * 128;
  const int tid = threadIdx.x;
  const int l = tid & 63, w = tid >> 6;
  const int wm = w >> 1, wn = w & 1;
  const int lr = l & 15, lo = l >> 4;
  const int srow = w * 8 + (l >> 3);        // staging row within a 32-row group
  const int sc = (l & 7) ^ ((l >> 3) & 7);  // pre-swizzled source chunk
  f32x4 acc[4][4] = {};
  for (int kt = 0; kt < K; kt += 64) {
    __syncthreads();
#pragma unroll
    for (int it = 0; it < 4; ++it) {
      int row = it * 32 + srow;
      gld_lds16(A + (size_t)(m0 + row) * K + kt + sc * 8,
                (char*)As + (it * 32 + w * 8) * 128);
      gld_lds16(Bt + (size_t)(n0 + row) * K + kt + sc * 8,
                (char*)Bs + (it * 32 + w * 8) * 128);
    }
    __syncthreads();
    bf16x8 af[4][2], bfr[4][2];
#pragma unroll
    for (int mi = 0; mi < 4; ++mi) {
      int row = wm * 64 + mi * 16 + lr;
#pragma unroll
      for (int ks = 0; ks < 2; ++ks) {
        int ch = (ks * 4 + lo) ^ (row & 7);
        af[mi][ks] = *reinterpret_cast<const bf16x8*>((const char*)As + row * 128 + ch * 16);
      }
    }
#pragma unroll
    for (int nj = 0; nj < 4; ++nj) {
      int row = wn * 64 + nj * 16 + lr;
#pragma unroll
      for (int ks = 0; ks < 2; ++ks) {
        int ch = (ks * 4 + lo) ^ (row & 7);
        bfr[nj][ks] = *reinterpret_cast<const bf16x8*>((const char*)Bs + row * 128 + ch * 16);
      }
    }
#pragma unroll
    for (int mi = 0; mi < 4; ++mi)
#pragma unroll
      for (int nj = 0; nj < 4; ++nj) {
        acc[mi][nj] = __builtin_amdgcn_mfma_f32_16x16x32_bf16(af[mi][0], bfr[nj][0], acc[mi][nj], 0, 0, 0);
        acc[mi][nj] = __builtin_amdgcn_mfma_f32_16x16x32_bf16(af[mi][1], bfr[nj][1], acc[mi][nj], 0, 0, 0);
      }
  }
  // epilogue: C/D layout col=lane&15, row=(lane>>4)*4+reg
#pragma unroll
  for (int mi = 0; mi < 4; ++mi) {
    int row = m0 + wm * 64 + mi * 16 + lo * 4;
#pragma unroll
    for (int nj = 0; nj < 4; ++nj) {
      int col = n0 + wn * 64 + nj * 16 + lr;
      float bv = bias[col];
#pragma unroll
      for (int r = 0; r < 4; ++r) {
        float v = acc[mi][nj][r] + bv;
        if (F32OUT) ((float*)Cout)[(size_t)(row + r) * N + col] = v;
        else        ((u16*)Cout)[(size_t)(row + r) * N + col] = f2bf(v);
      }
    }
  }
}

// ---------------- flash attention ----------------
// grid (S/64, NQ, B); 4 waves x 16 q-rows; KV tiles of 32; HD=64.
// QKV buffer: [B*S][3072] bf16, cols: Q h*64+d | K 2048+kv*64+d | V 2560+kv*64+d
__global__ __launch_bounds__(256, 4) void k_attn(const u16* __restrict__ QKV,
                                                 u16* __restrict__ Oa) {
  constexpr int S = 2048, LDQ = 3072;
  __shared__ __align__(16) u16 Ks[32 * 64];      // row-swizzled (chunk ^= row&7)
  __shared__ __align__(16) u16 Vt[64 * 40];      // V^T [d][key], stride 40 (80B)
  __shared__ __align__(16) u16 Ps[4][16 * 40];   // per-wave P [q][key], stride 40
  const int qt = blockIdx.x, h = blockIdx.y, b = blockIdx.z;
  const int kvh = h >> 2;                        // g = 4 queries per kv head
  const int tid = threadIdx.x, l = tid & 63, w = tid >> 6;
  const int lr = l & 15, lo = l >> 4;
  const size_t base = (size_t)b * S * LDQ;
  const u16* Qg = QKV + base + h * 64;
  const u16* Kg = QKV + base + 2048 + kvh * 64;
  const u16* Vg = QKV + base + 2560 + kvh * 64;
  const int qrow = qt * 64 + w * 16 + lr;
  bf16x8 aq0 = *reinterpret_cast<const bf16x8*>(Qg + (size_t)qrow * LDQ + lo * 8);
  bf16x8 aq1 = *reinterpret_cast<const bf16x8*>(Qg + (size_t)qrow * LDQ + 32 + lo * 8);
  const float SCL = 0.125f * 1.44269504088896341f;  // 1/sqrt(64) * log2(e)
  f32x4 acc[4] = {};
  float mrow[4] = {-1e30f, -1e30f, -1e30f, -1e30f};
  float lsum[4] = {0.f, 0.f, 0.f, 0.f};
  const int krow = w * 8 + (l >> 3);
  const int ksc = (l & 7) ^ ((l >> 3) & 7);
  const int vrow = tid & 31, vdg = tid >> 5;
  for (int kt = 0; kt < S; kt += 32) {
    __syncthreads();
    gld_lds16(Kg + (size_t)(kt + krow) * LDQ + ksc * 8, (char*)Ks + w * 8 * 128);
    u16x8 vv = *reinterpret_cast<const u16x8*>(Vg + (size_t)(kt + vrow) * LDQ + vdg * 8);
#pragma unroll
    for (int j = 0; j < 8; ++j) Vt[(vdg * 8 + j) * 40 + vrow] = vv[j];
    __syncthreads();
    // QK^T: scores[q][key], 2 key n-tiles
    f32x4 s0, s1;
    {
      int row0 = lr, row1 = 16 + lr;
      bf16x8 b00 = *reinterpret_cast<const bf16x8*>((const char*)Ks + row0 * 128 + ((lo ^ (row0 & 7)) * 16));
      bf16x8 b01 = *reinterpret_cast<const bf16x8*>((const char*)Ks + row0 * 128 + (((4 + lo) ^ (row0 & 7)) * 16));
      bf16x8 b10 = *reinterpret_cast<const bf16x8*>((const char*)Ks + row1 * 128 + ((lo ^ (row1 & 7)) * 16));
      bf16x8 b11 = *reinterpret_cast<const bf16x8*>((const char*)Ks + row1 * 128 + (((4 + lo) ^ (row1 & 7)) * 16));
      f32x4 z0 = {}, z1 = {};
      z0 = __builtin_amdgcn_mfma_f32_16x16x32_bf16(aq0, b00, z0, 0, 0, 0);
      z0 = __builtin_amdgcn_mfma_f32_16x16x32_bf16(aq1, b01, z0, 0, 0, 0);
      z1 = __builtin_amdgcn_mfma_f32_16x16x32_bf16(aq0, b10, z1, 0, 0, 0);
      z1 = __builtin_amdgcn_mfma_f32_16x16x32_bf16(aq1, b11, z1, 0, 0, 0);
      s0 = z0; s1 = z1;
    }
    // online softmax (base-2 domain); rows = lo*4+r, cols = lr (+16)
#pragma unroll
    for (int r = 0; r < 4; ++r) {
      float a0 = s0[r] * SCL, a1 = s1[r] * SCL;
      float mx = fmaxf(a0, a1);
      mx = fmaxf(mx, __shfl_xor(mx, 1, 64));
      mx = fmaxf(mx, __shfl_xor(mx, 2, 64));
      mx = fmaxf(mx, __shfl_xor(mx, 4, 64));
      mx = fmaxf(mx, __shfl_xor(mx, 8, 64));
      float mnew = fmaxf(mrow[r], mx);
      float alpha = exp2f(mrow[r] - mnew);
      mrow[r] = mnew;
      float p0 = exp2f(a0 - mnew), p1 = exp2f(a1 - mnew);
      float ps = p0 + p1;
      ps += __shfl_xor(ps, 1, 64);
      ps += __shfl_xor(ps, 2, 64);
      ps += __shfl_xor(ps, 4, 64);
      ps += __shfl_xor(ps, 8, 64);
      lsum[r] = lsum[r] * alpha + ps;
#pragma unroll
      for (int nj = 0; nj < 4; ++nj) acc[nj][r] *= alpha;
      Ps[w][(lo * 4 + r) * 40 + lr] = f2bf(p0);
      Ps[w][(lo * 4 + r) * 40 + lr + 16] = f2bf(p1);
    }
    // wave-internal LDS visibility for P (same wave writes & reads)
    asm volatile("s_waitcnt lgkmcnt(0)" ::: "memory");
    bf16x8 pa = *reinterpret_cast<const bf16x8*>((const char*)Ps[w] + lr * 80 + lo * 16);
#pragma unroll
    for (int nj = 0; nj < 4; ++nj) {
      bf16x8 bv = *reinterpret_cast<const bf16x8*>((const char*)Vt + (nj * 16 + lr) * 80 + lo * 16);
      acc[nj] = __builtin_amdgcn_mfma_f32_16x16x32_bf16(pa, bv, acc[nj], 0, 0, 0);
    }
  }
  const size_t orow = (size_t)b * S + qt * 64 + w * 16 + lo * 4;
#pragma unroll
  for (int nj = 0; nj < 4; ++nj) {
    int col = h * 64 + nj * 16 + lr;
#pragma unroll
    for (int r = 0; r < 4; ++r) {
      Oa[(orow + r) * 2048 + col] = f2bf(acc[nj][r] / lsum[r]);
    }
  }
}

// ---------------- host ----------------
extern "C" void kernel_launch(void* const* d_in, const int* in_sizes, int n_in,
                              void* d_out, int out_size, void* d_ws, size_t ws_size,
                              hipStream_t stream) {
  const float* x  = (const float*)d_in[0];
  const float* Wq = (const float*)d_in[1];
  const float* bq = (const float*)d_in[2];
  const float* Wk = (const float*)d_in[3];
  const float* bk = (const float*)d_in[4];
  const float* Wv = (const float*)d_in[5];
  const float* bv = (const float*)d_in[6];
  const float* Wo = (const float*)d_in[7];
  const float* bo = (const float*)d_in[8];
  float* out = (float*)d_out;
  char* ws = (char*)d_ws;

  u16*   xb    = (u16*)(ws + 0);           // [4096][2048] bf16   16.78 MB
  u16*   wqkvT = (u16*)(ws + 16777216);    // [3072][2048] bf16   12.58 MB
  u16*   woT   = (u16*)(ws + 29360128);    // [2048][2048] bf16    8.39 MB
  u16*   qkv   = (u16*)(ws + 37748736);    // [4096][3072] bf16   25.17 MB
  u16*   attn  = (u16*)(ws + 62914560);    // [4096][2048] bf16   16.78 MB
  float* bcat  = (float*)(ws + 79691776);  // [3072] f32

  k_cast<<<4096, 256, 0, stream>>>(x, xb, 1048576);
  k_transpose_cast<<<dim3(32, 32), 256, 0, stream>>>(Wq, wqkvT, 2048, 2048);
  k_transpose_cast<<<dim3(8, 32), 256, 0, stream>>>(Wk, wqkvT + (size_t)2048 * 2048, 2048, 512);
  k_transpose_cast<<<dim3(8, 32), 256, 0, stream>>>(Wv, wqkvT + (size_t)2560 * 2048, 2048, 512);
  k_transpose_cast<<<dim3(32, 32), 256, 0, stream>>>(Wo, woT, 2048, 2048);
  k_concat_bias<<<12, 256, 0, stream>>>(bq, bk, bv, bcat);
  k_gemm<false><<<dim3(24, 32), 256, 0, stream>>>(xb, wqkvT, bcat, qkv, 4096, 3072, 2048);
  k_attn<<<dim3(32, 32, 2), 256, 0, stream>>>(qkv, attn);
  k_gemm<true><<<dim3(16, 32), 256, 0, stream>>>(attn, woT, bo, out, 4096, 2048, 2048);
}

// Round 3
// 318.351 us; speedup vs baseline: 1.5134x; 1.5134x over previous
//
#include <hip/hip_runtime.h>
#include <cstdint>
#include <cstddef>

typedef unsigned short u16;
typedef __bf16 bf16x8 __attribute__((ext_vector_type(8)));
typedef float f32x4 __attribute__((ext_vector_type(4)));
typedef unsigned short u16x4 __attribute__((ext_vector_type(4)));
typedef unsigned short u16x8 __attribute__((ext_vector_type(8)));
typedef __attribute__((address_space(1))) unsigned int as1_uint;
typedef __attribute__((address_space(3))) unsigned int as3_uint;

__device__ __forceinline__ u16 f2bf(float f) {
  uint32_t u = __builtin_bit_cast(uint32_t, f);
  u += 0x7FFFu + ((u >> 16) & 1u);   // RNE to bf16
  return (u16)(u >> 16);
}

__device__ __forceinline__ uint32_t pack2bf(float a, float b) {
  return (uint32_t)f2bf(a) | ((uint32_t)f2bf(b) << 16);
}

__device__ __forceinline__ void gld_lds16(const void* g, void* l) {
  __builtin_amdgcn_global_load_lds((as1_uint*)g, (as3_uint*)l, 16, 0, 0);
}

// ---------------- cast fp32 -> bf16, 8 elems/thread ----------------
__global__ __launch_bounds__(256) void k_cast(const float* __restrict__ in,
                                              u16* __restrict__ out, int n8) {
  int i = blockIdx.x * 256 + threadIdx.x;
  if (i >= n8) return;
  const float4* p = reinterpret_cast<const float4*>(in) + (size_t)i * 2;
  float4 a = p[0], b = p[1];
  u16x8 r;
  r[0] = f2bf(a.x); r[1] = f2bf(a.y); r[2] = f2bf(a.z); r[3] = f2bf(a.w);
  r[4] = f2bf(b.x); r[5] = f2bf(b.y); r[6] = f2bf(b.z); r[7] = f2bf(b.w);
  *reinterpret_cast<u16x8*>(out + (size_t)i * 8) = r;
}

// ---------------- W [K][N] f32  ->  Wt [N][K] bf16 ----------------
__global__ __launch_bounds__(256) void k_transpose_cast(const float* __restrict__ W,
                                                        u16* __restrict__ Wt,
                                                        int K, int N) {
  __shared__ u16 tile[64][72];
  int k0 = blockIdx.y * 64, n0 = blockIdx.x * 64;
  int r = threadIdx.x >> 4;
  int c4 = (threadIdx.x & 15) * 4;
#pragma unroll
  for (int i = 0; i < 4; ++i) {
    int kk = r + i * 16;
    float4 v = *reinterpret_cast<const float4*>(W + (size_t)(k0 + kk) * N + n0 + c4);
    tile[kk][c4 + 0] = f2bf(v.x); tile[kk][c4 + 1] = f2bf(v.y);
    tile[kk][c4 + 2] = f2bf(v.z); tile[kk][c4 + 3] = f2bf(v.w);
  }
  __syncthreads();
#pragma unroll
  for (int i = 0; i < 4; ++i) {
    int nn = r + i * 16;
    u16x4 o;
    o[0] = tile[c4 + 0][nn]; o[1] = tile[c4 + 1][nn];
    o[2] = tile[c4 + 2][nn]; o[3] = tile[c4 + 3][nn];
    *reinterpret_cast<u16x4*>(Wt + (size_t)(n0 + nn) * K + k0 + c4) = o;
  }
}

// ---------------- concat qkv bias ----------------
__global__ __launch_bounds__(256) void k_concat_bias(const float* __restrict__ bq,
                                                     const float* __restrict__ bk,
                                                     const float* __restrict__ bv,
                                                     float* __restrict__ out) {
  int i = blockIdx.x * 256 + threadIdx.x;
  if (i >= 3072) return;
  float v;
  if (i < 2048) v = bq[i];
  else if (i < 2560) v = bk[i - 2048];
  else v = bv[i - 2560];
  out[i] = v;
}

// ---------------- bf16 GEMM: C = A[M][K] @ Bt[N][K]^T + bias ----------------
// 128x128 tile, BK=64, 4 waves (2x2), 16x16x32 MFMA.
template <bool F32OUT>
__global__ __launch_bounds__(256) void k_gemm(const u16* __restrict__ A,
                                              const u16* __restrict__ Bt,
                                              const float* __restrict__ bias,
                                              void* __restrict__ Cout,
                                              int M, int N, int K) {
  __shared__ __align__(16) u16 As[128 * 64];
  __shared__ __align__(16) u16 Bs[128 * 64];
  const int m0 = blockIdx.y * 128, n0 = blockIdx.x * 128;
  const int tid = threadIdx.x;
  const int l = tid & 63, w = tid >> 6;
  const int wm = w >> 1, wn = w & 1;
  const int lr = l & 15, lo = l >> 4;
  const int srow = w * 8 + (l >> 3);
  const int sc = (l & 7) ^ ((l >> 3) & 7);
  f32x4 acc[4][4] = {};
  for (int kt = 0; kt < K; kt += 64) {
    __syncthreads();
#pragma unroll
    for (int it = 0; it < 4; ++it) {
      int row = it * 32 + srow;
      gld_lds16(A + (size_t)(m0 + row) * K + kt + sc * 8,
                (char*)As + (it * 32 + w * 8) * 128);
      gld_lds16(Bt + (size_t)(n0 + row) * K + kt + sc * 8,
                (char*)Bs + (it * 32 + w * 8) * 128);
    }
    __syncthreads();
    bf16x8 af[4][2], bfr[4][2];
#pragma unroll
    for (int mi = 0; mi < 4; ++mi) {
      int row = wm * 64 + mi * 16 + lr;
#pragma unroll
      for (int ks = 0; ks < 2; ++ks) {
        int ch = (ks * 4 + lo) ^ (row & 7);
        af[mi][ks] = *reinterpret_cast<const bf16x8*>((const char*)As + row * 128 + ch * 16);
      }
    }
#pragma unroll
    for (int nj = 0; nj < 4; ++nj) {
      int row = wn * 64 + nj * 16 + lr;
#pragma unroll
      for (int ks = 0; ks < 2; ++ks) {
        int ch = (ks * 4 + lo) ^ (row & 7);
        bfr[nj][ks] = *reinterpret_cast<const bf16x8*>((const char*)Bs + row * 128 + ch * 16);
      }
    }
#pragma unroll
    for (int mi = 0; mi < 4; ++mi)
#pragma unroll
      for (int nj = 0; nj < 4; ++nj) {
        acc[mi][nj] = __builtin_amdgcn_mfma_f32_16x16x32_bf16(af[mi][0], bfr[nj][0], acc[mi][nj], 0, 0, 0);
        acc[mi][nj] = __builtin_amdgcn_mfma_f32_16x16x32_bf16(af[mi][1], bfr[nj][1], acc[mi][nj], 0, 0, 0);
      }
  }
#pragma unroll
  for (int mi = 0; mi < 4; ++mi) {
    int row = m0 + wm * 64 + mi * 16 + lo * 4;
#pragma unroll
    for (int nj = 0; nj < 4; ++nj) {
      int col = n0 + wn * 64 + nj * 16 + lr;
      float bv = bias[col];
#pragma unroll
      for (int r = 0; r < 4; ++r) {
        float v = acc[mi][nj][r] + bv;
        if (F32OUT) ((float*)Cout)[(size_t)(row + r) * N + col] = v;
        else        ((u16*)Cout)[(size_t)(row + r) * N + col] = f2bf(v);
      }
    }
  }
}

// ---------------- flash attention, swapped-QK^T + lane-local softmax ----------------
// grid (S/64, NQ, B); 4 waves x 16 q-rows; KVBLK=64; HD=64.
// Swapped: S^T = mfma(K_frag, Q_frag) -> lane (lo,lr) holds S[key=t*16+lo*4+r][q=lr].
// Softmax over keys: 15 in-lane ops + 2 shfl. P stored [q][key] -> PV A-frag direct.
__global__ __launch_bounds__(256, 4) void k_attn(const u16* __restrict__ QKV,
                                                 u16* __restrict__ Oa) {
  constexpr int S = 2048, LDQ = 3072, LDV = 72, LDP = 72;
  __shared__ __align__(16) u16 Ks[64 * 64];        // row-swizzled (chunk ^= row&7)
  __shared__ __align__(16) u16 Vt[64 * LDV];       // V^T [d][key]
  __shared__ __align__(16) u16 Ps[4][16 * LDP];    // per-wave P [q][key]
  const int qt = blockIdx.x, h = blockIdx.y, b = blockIdx.z;
  const int kvh = h >> 2;
  const int tid = threadIdx.x, l = tid & 63, w = tid >> 6;
  const int lr = l & 15, lo = l >> 4;
  const size_t base = (size_t)b * S * LDQ;
  const u16* Qg = QKV + base + h * 64;
  const u16* Kg = QKV + base + 2048 + kvh * 64;
  const u16* Vg = QKV + base + 2560 + kvh * 64;
  const int qrow = qt * 64 + w * 16 + lr;
  const bf16x8 aq0 = *reinterpret_cast<const bf16x8*>(Qg + (size_t)qrow * LDQ + lo * 8);
  const bf16x8 aq1 = *reinterpret_cast<const bf16x8*>(Qg + (size_t)qrow * LDQ + 32 + lo * 8);
  const float SCL = 0.125f * 1.44269504088896341f;   // 1/sqrt(64) * log2(e)
  f32x4 acc[4] = {};
  float mrun = -1e30f, lsum = 0.f;
  const int krow = w * 8 + (l >> 3);
  const int ksc = (l & 7) ^ ((l >> 3) & 7);
  for (int kt = 0; kt < S; kt += 64) {
    __syncthreads();
    // K: 64x64 via global_load_lds (linear dest, pre-swizzled source chunk)
    gld_lds16(Kg + (size_t)(kt + krow) * LDQ + ksc * 8, (char*)Ks + (w * 8) * 128);
    gld_lds16(Kg + (size_t)(kt + 32 + krow) * LDQ + ksc * 8, (char*)Ks + (32 + w * 8) * 128);
    // V: wave w owns d-rows w*16..w*16+15; lane = key. Scatter-write V^T (2-way banks).
    u16x8 v0 = *reinterpret_cast<const u16x8*>(Vg + (size_t)(kt + l) * LDQ + w * 16);
    u16x8 v1 = *reinterpret_cast<const u16x8*>(Vg + (size_t)(kt + l) * LDQ + w * 16 + 8);
#pragma unroll
    for (int j = 0; j < 8; ++j) {
      Vt[(w * 16 + j) * LDV + l] = v0[j];
      Vt[(w * 16 + 8 + j) * LDV + l] = v1[j];
    }
    __syncthreads();
    // QK^T swapped: z[t][r] = S[key=t*16+lo*4+r][q=lr]
    float p[16];
    __builtin_amdgcn_s_setprio(1);
#pragma unroll
    for (int t = 0; t < 4; ++t) {
      const int row = t * 16 + lr;
      bf16x8 k0 = *reinterpret_cast<const bf16x8*>((const char*)Ks + row * 128 + ((lo ^ (row & 7)) * 16));
      bf16x8 k1 = *reinterpret_cast<const bf16x8*>((const char*)Ks + row * 128 + (((4 + lo) ^ (row & 7)) * 16));
      f32x4 zz = {};
      zz = __builtin_amdgcn_mfma_f32_16x16x32_bf16(k0, aq0, zz, 0, 0, 0);
      zz = __builtin_amdgcn_mfma_f32_16x16x32_bf16(k1, aq1, zz, 0, 0, 0);
#pragma unroll
      for (int r = 0; r < 4; ++r) p[t * 4 + r] = zz[r] * SCL;
    }
    __builtin_amdgcn_s_setprio(0);
    // tile max for q=lr: 15 in-lane fmax + 2 shfl (xor16, xor32)
    float tm = fmaxf(fmaxf(fmaxf(p[0], p[1]), fmaxf(p[2], p[3])),
                     fmaxf(fmaxf(p[4], p[5]), fmaxf(p[6], p[7])));
    tm = fmaxf(tm, fmaxf(fmaxf(fmaxf(p[8], p[9]), fmaxf(p[10], p[11])),
                         fmaxf(fmaxf(p[12], p[13]), fmaxf(p[14], p[15]))));
    tm = fmaxf(tm, __shfl_xor(tm, 16, 64));
    tm = fmaxf(tm, __shfl_xor(tm, 32, 64));
    if (__all(tm <= mrun)) {
      // defer-max: running max unchanged, no rescale
#pragma unroll
      for (int i = 0; i < 16; ++i) p[i] = __builtin_amdgcn_exp2f(p[i] - mrun);
    } else {
      float mnew = fmaxf(mrun, tm);
      float alpha = __builtin_amdgcn_exp2f(mrun - mnew);
      mrun = mnew;
#pragma unroll
      for (int i = 0; i < 16; ++i) p[i] = __builtin_amdgcn_exp2f(p[i] - mnew);
      lsum *= alpha;
#pragma unroll
      for (int r = 0; r < 4; ++r) {
        float ar = __shfl(alpha, lo * 4 + r, 64);   // alpha for acc-row q=lo*4+r
#pragma unroll
        for (int nj = 0; nj < 4; ++nj) acc[nj][r] *= ar;
      }
    }
    float rs = (((p[0] + p[1]) + (p[2] + p[3])) + ((p[4] + p[5]) + (p[6] + p[7])))
             + (((p[8] + p[9]) + (p[10] + p[11])) + ((p[12] + p[13]) + (p[14] + p[15])));
    rs += __shfl_xor(rs, 16, 64);
    rs += __shfl_xor(rs, 32, 64);
    lsum += rs;
    // pack P -> Ps[w][q=lr][key], packed u32 pairs (merge to b64)
#pragma unroll
    for (int t = 0; t < 4; ++t) {
      uint32_t* dst = reinterpret_cast<uint32_t*>(&Ps[w][lr * LDP + t * 16 + lo * 4]);
      dst[0] = pack2bf(p[t * 4 + 0], p[t * 4 + 1]);
      dst[1] = pack2bf(p[t * 4 + 2], p[t * 4 + 3]);
    }
    asm volatile("s_waitcnt lgkmcnt(0)" ::: "memory");   // same-wave P visibility
    __builtin_amdgcn_sched_barrier(0);                   // rule 18 fence
    const bf16x8 pa0 = *reinterpret_cast<const bf16x8*>(&Ps[w][lr * LDP + lo * 8]);
    const bf16x8 pa1 = *reinterpret_cast<const bf16x8*>(&Ps[w][lr * LDP + 32 + lo * 8]);
    __builtin_amdgcn_s_setprio(1);
#pragma unroll
    for (int nj = 0; nj < 4; ++nj) {
      const bf16x8 bv0 = *reinterpret_cast<const bf16x8*>(&Vt[(nj * 16 + lr) * LDV + lo * 8]);
      const bf16x8 bv1 = *reinterpret_cast<const bf16x8*>(&Vt[(nj * 16 + lr) * LDV + 32 + lo * 8]);
      acc[nj] = __builtin_amdgcn_mfma_f32_16x16x32_bf16(pa0, bv0, acc[nj], 0, 0, 0);
      acc[nj] = __builtin_amdgcn_mfma_f32_16x16x32_bf16(pa1, bv1, acc[nj], 0, 0, 0);
    }
    __builtin_amdgcn_s_setprio(0);
  }
  float lf[4];
#pragma unroll
  for (int r = 0; r < 4; ++r) lf[r] = 1.0f / __shfl(lsum, lo * 4 + r, 64);
  const size_t orow = (size_t)b * S + qt * 64 + w * 16 + lo * 4;
#pragma unroll
  for (int nj = 0; nj < 4; ++nj) {
    const int col = h * 64 + nj * 16 + lr;
#pragma unroll
    for (int r = 0; r < 4; ++r)
      Oa[(orow + r) * 2048 + col] = f2bf(acc[nj][r] * lf[r]);
  }
}

// ---------------- host ----------------
extern "C" void kernel_launch(void* const* d_in, const int* in_sizes, int n_in,
                              void* d_out, int out_size, void* d_ws, size_t ws_size,
                              hipStream_t stream) {
  const float* x  = (const float*)d_in[0];
  const float* Wq = (const float*)d_in[1];
  const float* bq = (const float*)d_in[2];
  const float* Wk = (const float*)d_in[3];
  const float* bk = (const float*)d_in[4];
  const float* Wv = (const float*)d_in[5];
  const float* bv = (const float*)d_in[6];
  const float* Wo = (const float*)d_in[7];
  const float* bo = (const float*)d_in[8];
  float* out = (float*)d_out;
  char* ws = (char*)d_ws;

  u16*   xb    = (u16*)(ws + 0);           // [4096][2048] bf16   16.78 MB
  u16*   wqkvT = (u16*)(ws + 16777216);    // [3072][2048] bf16   12.58 MB
  u16*   woT   = (u16*)(ws + 29360128);    // [2048][2048] bf16    8.39 MB
  u16*   qkv   = (u16*)(ws + 37748736);    // [4096][3072] bf16   25.17 MB
  u16*   attn  = (u16*)(ws + 62914560);    // [4096][2048] bf16   16.78 MB
  float* bcat  = (float*)(ws + 79691776);  // [3072] f32

  k_cast<<<4096, 256, 0, stream>>>(x, xb, 1048576);
  k_transpose_cast<<<dim3(32, 32), 256, 0, stream>>>(Wq, wqkvT, 2048, 2048);
  k_transpose_cast<<<dim3(8, 32), 256, 0, stream>>>(Wk, wqkvT + (size_t)2048 * 2048, 2048, 512);
  k_transpose_cast<<<dim3(8, 32), 256, 0, stream>>>(Wv, wqkvT + (size_t)2560 * 2048, 2048, 512);
  k_transpose_cast<<<dim3(32, 32), 256, 0, stream>>>(Wo, woT, 2048, 2048);
  k_concat_bias<<<12, 256, 0, stream>>>(bq, bk, bv, bcat);
  k_gemm<false><<<dim3(24, 32), 256, 0, stream>>>(xb, wqkvT, bcat, qkv, 4096, 3072, 2048);
  k_attn<<<dim3(32, 32, 2), 256, 0, stream>>>(qkv, attn);
  k_gemm<true><<<dim3(16, 32), 256, 0, stream>>>(attn, woT, bo, out, 4096, 2048, 2048);
}

// Round 4
// 308.399 us; speedup vs baseline: 1.5622x; 1.0323x over previous
//
#include <hip/hip_runtime.h>
#include <cstdint>
#include <cstddef>

typedef unsigned short u16;
typedef __bf16 bf16x8 __attribute__((ext_vector_type(8)));
typedef float f32x4 __attribute__((ext_vector_type(4)));
typedef unsigned short u16x4 __attribute__((ext_vector_type(4)));
typedef unsigned short u16x8 __attribute__((ext_vector_type(8)));
typedef uint32_t u32x4 __attribute__((ext_vector_type(4)));
typedef __attribute__((address_space(1))) unsigned int as1_uint;
typedef __attribute__((address_space(3))) unsigned int as3_uint;

__device__ __forceinline__ u16 f2bf(float f) {
  uint32_t u = __builtin_bit_cast(uint32_t, f);
  u += 0x7FFFu + ((u >> 16) & 1u);   // RNE to bf16
  return (u16)(u >> 16);
}

__device__ __forceinline__ uint32_t pack2bf(float a, float b) {
  return (uint32_t)f2bf(a) | ((uint32_t)f2bf(b) << 16);
}

__device__ __forceinline__ void gld_lds16(const void* g, void* l) {
  __builtin_amdgcn_global_load_lds((as1_uint*)g, (as3_uint*)l, 16, 0, 0);
}

// ---------------- cast fp32 -> bf16, 8 elems/thread ----------------
__global__ __launch_bounds__(256) void k_cast(const float* __restrict__ in,
                                              u16* __restrict__ out, int n8) {
  int i = blockIdx.x * 256 + threadIdx.x;
  if (i >= n8) return;
  const float4* p = reinterpret_cast<const float4*>(in) + (size_t)i * 2;
  float4 a = p[0], b = p[1];
  u16x8 r;
  r[0] = f2bf(a.x); r[1] = f2bf(a.y); r[2] = f2bf(a.z); r[3] = f2bf(a.w);
  r[4] = f2bf(b.x); r[5] = f2bf(b.y); r[6] = f2bf(b.z); r[7] = f2bf(b.w);
  *reinterpret_cast<u16x8*>(out + (size_t)i * 8) = r;
}

// ---------------- W [K][N] f32  ->  Wt [N][K] bf16 ----------------
__global__ __launch_bounds__(256) void k_transpose_cast(const float* __restrict__ W,
                                                        u16* __restrict__ Wt,
                                                        int K, int N) {
  __shared__ u16 tile[64][72];
  int k0 = blockIdx.y * 64, n0 = blockIdx.x * 64;
  int r = threadIdx.x >> 4;
  int c4 = (threadIdx.x & 15) * 4;
#pragma unroll
  for (int i = 0; i < 4; ++i) {
    int kk = r + i * 16;
    float4 v = *reinterpret_cast<const float4*>(W + (size_t)(k0 + kk) * N + n0 + c4);
    tile[kk][c4 + 0] = f2bf(v.x); tile[kk][c4 + 1] = f2bf(v.y);
    tile[kk][c4 + 2] = f2bf(v.z); tile[kk][c4 + 3] = f2bf(v.w);
  }
  __syncthreads();
#pragma unroll
  for (int i = 0; i < 4; ++i) {
    int nn = r + i * 16;
    u16x4 o;
    o[0] = tile[c4 + 0][nn]; o[1] = tile[c4 + 1][nn];
    o[2] = tile[c4 + 2][nn]; o[3] = tile[c4 + 3][nn];
    *reinterpret_cast<u16x4*>(Wt + (size_t)(n0 + nn) * K + k0 + c4) = o;
  }
}

// ---------------- concat qkv bias ----------------
__global__ __launch_bounds__(256) void k_concat_bias(const float* __restrict__ bq,
                                                     const float* __restrict__ bk,
                                                     const float* __restrict__ bv,
                                                     float* __restrict__ out) {
  int i = blockIdx.x * 256 + threadIdx.x;
  if (i >= 3072) return;
  float v;
  if (i < 2048) v = bq[i];
  else if (i < 2560) v = bk[i - 2048];
  else v = bv[i - 2560];
  out[i] = v;
}

// ---------------- bf16 GEMM: C = A[M][K] @ Bt[N][K]^T + bias ----------------
// 128x128 tile, BK=64, 4 waves (2x2), 16x16x32 MFMA. (m97 structure)
template <bool F32OUT>
__global__ __launch_bounds__(256) void k_gemm(const u16* __restrict__ A,
                                              const u16* __restrict__ Bt,
                                              const float* __restrict__ bias,
                                              void* __restrict__ Cout,
                                              int M, int N, int K) {
  __shared__ __align__(16) u16 As[128 * 64];
  __shared__ __align__(16) u16 Bs[128 * 64];
  const int m0 = blockIdx.y * 128, n0 = blockIdx.x * 128;
  const int tid = threadIdx.x;
  const int l = tid & 63, w = tid >> 6;
  const int wm = w >> 1, wn = w & 1;
  const int lr = l & 15, lo = l >> 4;
  const int srow = w * 8 + (l >> 3);
  const int sc = (l & 7) ^ ((l >> 3) & 7);
  f32x4 acc[4][4] = {};
  for (int kt = 0; kt < K; kt += 64) {
    __syncthreads();
#pragma unroll
    for (int it = 0; it < 4; ++it) {
      int row = it * 32 + srow;
      gld_lds16(A + (size_t)(m0 + row) * K + kt + sc * 8,
                (char*)As + (it * 32 + w * 8) * 128);
      gld_lds16(Bt + (size_t)(n0 + row) * K + kt + sc * 8,
                (char*)Bs + (it * 32 + w * 8) * 128);
    }
    __syncthreads();
    bf16x8 af[4][2], bfr[4][2];
#pragma unroll
    for (int mi = 0; mi < 4; ++mi) {
      int row = wm * 64 + mi * 16 + lr;
#pragma unroll
      for (int ks = 0; ks < 2; ++ks) {
        int ch = (ks * 4 + lo) ^ (row & 7);
        af[mi][ks] = *reinterpret_cast<const bf16x8*>((const char*)As + row * 128 + ch * 16);
      }
    }
#pragma unroll
    for (int nj = 0; nj < 4; ++nj) {
      int row = wn * 64 + nj * 16 + lr;
#pragma unroll
      for (int ks = 0; ks < 2; ++ks) {
        int ch = (ks * 4 + lo) ^ (row & 7);
        bfr[nj][ks] = *reinterpret_cast<const bf16x8*>((const char*)Bs + row * 128 + ch * 16);
      }
    }
#pragma unroll
    for (int mi = 0; mi < 4; ++mi)
#pragma unroll
      for (int nj = 0; nj < 4; ++nj) {
        acc[mi][nj] = __builtin_amdgcn_mfma_f32_16x16x32_bf16(af[mi][0], bfr[nj][0], acc[mi][nj], 0, 0, 0);
        acc[mi][nj] = __builtin_amdgcn_mfma_f32_16x16x32_bf16(af[mi][1], bfr[nj][1], acc[mi][nj], 0, 0, 0);
      }
  }
#pragma unroll
  for (int mi = 0; mi < 4; ++mi) {
    int row = m0 + wm * 64 + mi * 16 + lo * 4;
#pragma unroll
    for (int nj = 0; nj < 4; ++nj) {
      int col = n0 + wn * 64 + nj * 16 + lr;
      float bv = bias[col];
#pragma unroll
      for (int r = 0; r < 4; ++r) {
        float v = acc[mi][nj][r] + bv;
        if (F32OUT) ((float*)Cout)[(size_t)(row + r) * N + col] = v;
        else        ((u16*)Cout)[(size_t)(row + r) * N + col] = f2bf(v);
      }
    }
  }
}

// ---------------- flash attention, swapped-QK^T + in-register P ----------------
// grid (S/64, NQ, B); 4 waves x 16 q-rows; KVBLK=64; HD=64.
// S^T = mfma(K,Q): lane(lo,lr) holds S[key=16t+4lo+r][q=lr]. Softmax lane-local.
// P redistribution to PV A-frag layout via v_permlane32_swap + v_permlane16_swap
// (no LDS roundtrip): pa dword pairs (d0,d2)=pl16(pl32(w[t][0],w[t+1][0])) etc.
__global__ __launch_bounds__(256, 4) void k_attn(const u16* __restrict__ QKV,
                                                 u16* __restrict__ Oa) {
  constexpr int S = 2048, LDQ = 3072, LDV = 72;
  __shared__ __align__(16) u16 Ks[64 * 64];        // row-swizzled (chunk ^= row&7)
  __shared__ __align__(16) u16 Vt[64 * LDV];       // V^T [d][key]
  const int qt = blockIdx.x, h = blockIdx.y, b = blockIdx.z;
  const int kvh = h >> 2;
  const int tid = threadIdx.x, l = tid & 63, w = tid >> 6;
  const int lr = l & 15, lo = l >> 4;
  const size_t base = (size_t)b * S * LDQ;
  const u16* Qg = QKV + base + h * 64;
  const u16* Kg = QKV + base + 2048 + kvh * 64;
  const u16* Vg = QKV + base + 2560 + kvh * 64;
  const int qrow = qt * 64 + w * 16 + lr;
  const bf16x8 aq0 = *reinterpret_cast<const bf16x8*>(Qg + (size_t)qrow * LDQ + lo * 8);
  const bf16x8 aq1 = *reinterpret_cast<const bf16x8*>(Qg + (size_t)qrow * LDQ + 32 + lo * 8);
  const float SCL = 0.125f * 1.44269504088896341f;   // 1/sqrt(64) * log2(e)
  f32x4 acc[4] = {};
  float mrun = -1e30f, lsum = 0.f;
  const int krow = w * 8 + (l >> 3);
  const int ksc = (l & 7) ^ ((l >> 3) & 7);
  const int vkey = (l & 31) * 2;        // key pair owned by this lane
  const int vdh = (l >> 5) * 8;         // d-offset half within wave's 16 d-rows
  for (int kt = 0; kt < S; kt += 64) {
    __syncthreads();
    // K: 64x64 via global_load_lds (linear dest, pre-swizzled source chunk)
    gld_lds16(Kg + (size_t)(kt + krow) * LDQ + ksc * 8, (char*)Ks + (w * 8) * 128);
    gld_lds16(Kg + (size_t)(kt + 32 + krow) * LDQ + ksc * 8, (char*)Ks + (32 + w * 8) * 128);
    // V: lane owns keys (vkey, vkey+1) x 8 d-rows; packed b32 writes, conflict-free
    u16x8 va = *reinterpret_cast<const u16x8*>(Vg + (size_t)(kt + vkey) * LDQ + w * 16 + vdh);
    u16x8 vb = *reinterpret_cast<const u16x8*>(Vg + (size_t)(kt + vkey + 1) * LDQ + w * 16 + vdh);
#pragma unroll
    for (int j = 0; j < 8; ++j) {
      uint32_t pw = (uint32_t)va[j] | ((uint32_t)vb[j] << 16);
      *reinterpret_cast<uint32_t*>(&Vt[(w * 16 + vdh + j) * LDV + vkey]) = pw;
    }
    __syncthreads();
    // QK^T swapped: p[t*4+r] = S[key=16t+4lo+r][q=lr]
    float p[16];
    __builtin_amdgcn_s_setprio(1);
#pragma unroll
    for (int t = 0; t < 4; ++t) {
      const int row = t * 16 + lr;
      bf16x8 k0 = *reinterpret_cast<const bf16x8*>((const char*)Ks + row * 128 + ((lo ^ (row & 7)) * 16));
      bf16x8 k1 = *reinterpret_cast<const bf16x8*>((const char*)Ks + row * 128 + (((4 + lo) ^ (row & 7)) * 16));
      f32x4 zz = {};
      zz = __builtin_amdgcn_mfma_f32_16x16x32_bf16(k0, aq0, zz, 0, 0, 0);
      zz = __builtin_amdgcn_mfma_f32_16x16x32_bf16(k1, aq1, zz, 0, 0, 0);
#pragma unroll
      for (int r = 0; r < 4; ++r) p[t * 4 + r] = zz[r] * SCL;
    }
    __builtin_amdgcn_s_setprio(0);
    // tile max for q=lr: 15 in-lane fmax + 2 shfl
    float tm = fmaxf(fmaxf(fmaxf(p[0], p[1]), fmaxf(p[2], p[3])),
                     fmaxf(fmaxf(p[4], p[5]), fmaxf(p[6], p[7])));
    tm = fmaxf(tm, fmaxf(fmaxf(fmaxf(p[8], p[9]), fmaxf(p[10], p[11])),
                         fmaxf(fmaxf(p[12], p[13]), fmaxf(p[14], p[15]))));
    tm = fmaxf(tm, __shfl_xor(tm, 16, 64));
    tm = fmaxf(tm, __shfl_xor(tm, 32, 64));
    if (__all(tm <= mrun)) {
#pragma unroll
      for (int i = 0; i < 16; ++i) p[i] = __builtin_amdgcn_exp2f(p[i] - mrun);
    } else {
      float mnew = fmaxf(mrun, tm);
      float alpha = __builtin_amdgcn_exp2f(mrun - mnew);
      mrun = mnew;
#pragma unroll
      for (int i = 0; i < 16; ++i) p[i] = __builtin_amdgcn_exp2f(p[i] - mnew);
      lsum *= alpha;
#pragma unroll
      for (int r = 0; r < 4; ++r) {
        float ar = __shfl(alpha, lo * 4 + r, 64);   // alpha for acc-row q=lo*4+r
#pragma unroll
        for (int nj = 0; nj < 4; ++nj) acc[nj][r] *= ar;
      }
    }
    float rs = (((p[0] + p[1]) + (p[2] + p[3])) + ((p[4] + p[5]) + (p[6] + p[7])))
             + (((p[8] + p[9]) + (p[10] + p[11])) + ((p[12] + p[13]) + (p[14] + p[15])));
    rs += __shfl_xor(rs, 16, 64);
    rs += __shfl_xor(rs, 32, 64);
    lsum += rs;
    // pack P pairs: wt_i = pack(p[4t+2i], p[4t+2i+1]) covers keys 16t+4lo+2i,+1
    uint32_t w00 = pack2bf(p[0], p[1]),   w01 = pack2bf(p[2], p[3]);
    uint32_t w10 = pack2bf(p[4], p[5]),   w11 = pack2bf(p[6], p[7]);
    uint32_t w20 = pack2bf(p[8], p[9]),   w21 = pack2bf(p[10], p[11]);
    uint32_t w30 = pack2bf(p[12], p[13]), w31 = pack2bf(p[14], p[15]);
    // redistribute to A-frag layout: lane lo needs keys 8lo..8lo+7 (pa0), +32 (pa1)
    asm volatile("v_permlane32_swap_b32 %0, %1" : "+v"(w00), "+v"(w10));
    asm volatile("v_permlane16_swap_b32 %0, %1" : "+v"(w00), "+v"(w10));  // w00=d0 w10=d2
    asm volatile("v_permlane32_swap_b32 %0, %1" : "+v"(w01), "+v"(w11));
    asm volatile("v_permlane16_swap_b32 %0, %1" : "+v"(w01), "+v"(w11));  // w01=d1 w11=d3
    asm volatile("v_permlane32_swap_b32 %0, %1" : "+v"(w20), "+v"(w30));
    asm volatile("v_permlane16_swap_b32 %0, %1" : "+v"(w20), "+v"(w30));
    asm volatile("v_permlane32_swap_b32 %0, %1" : "+v"(w21), "+v"(w31));
    asm volatile("v_permlane16_swap_b32 %0, %1" : "+v"(w21), "+v"(w31));
    u32x4 pq0; pq0[0] = w00; pq0[1] = w01; pq0[2] = w10; pq0[3] = w11;
    u32x4 pq1; pq1[0] = w20; pq1[1] = w21; pq1[2] = w30; pq1[3] = w31;
    const bf16x8 pa0 = __builtin_bit_cast(bf16x8, pq0);
    const bf16x8 pa1 = __builtin_bit_cast(bf16x8, pq1);
    __builtin_amdgcn_s_setprio(1);
#pragma unroll
    for (int nj = 0; nj < 4; ++nj) {
      const bf16x8 bv0 = *reinterpret_cast<const bf16x8*>(&Vt[(nj * 16 + lr) * LDV + lo * 8]);
      const bf16x8 bv1 = *reinterpret_cast<const bf16x8*>(&Vt[(nj * 16 + lr) * LDV + 32 + lo * 8]);
      acc[nj] = __builtin_amdgcn_mfma_f32_16x16x32_bf16(pa0, bv0, acc[nj], 0, 0, 0);
      acc[nj] = __builtin_amdgcn_mfma_f32_16x16x32_bf16(pa1, bv1, acc[nj], 0, 0, 0);
    }
    __builtin_amdgcn_s_setprio(0);
  }
  float lf[4];
#pragma unroll
  for (int r = 0; r < 4; ++r) lf[r] = 1.0f / __shfl(lsum, lo * 4 + r, 64);
  const size_t orow = (size_t)b * S + qt * 64 + w * 16 + lo * 4;
#pragma unroll
  for (int nj = 0; nj < 4; ++nj) {
    const int col = h * 64 + nj * 16 + lr;
#pragma unroll
    for (int r = 0; r < 4; ++r)
      Oa[(orow + r) * 2048 + col] = f2bf(acc[nj][r] * lf[r]);
  }
}

// ---------------- host ----------------
extern "C" void kernel_launch(void* const* d_in, const int* in_sizes, int n_in,
                              void* d_out, int out_size, void* d_ws, size_t ws_size,
                              hipStream_t stream) {
  const float* x  = (const float*)d_in[0];
  const float* Wq = (const float*)d_in[1];
  const float* bq = (const float*)d_in[2];
  const float* Wk = (const float*)d_in[3];
  const float* bk = (const float*)d_in[4];
  const float* Wv = (const float*)d_in[5];
  const float* bv = (const float*)d_in[6];
  const float* Wo = (const float*)d_in[7];
  const float* bo = (const float*)d_in[8];
  float* out = (float*)d_out;
  char* ws = (char*)d_ws;

  u16*   xb    = (u16*)(ws + 0);           // [4096][2048] bf16   16.78 MB
  u16*   wqkvT = (u16*)(ws + 16777216);    // [3072][2048] bf16   12.58 MB
  u16*   woT   = (u16*)(ws + 29360128);    // [2048][2048] bf16    8.39 MB
  u16*   qkv   = (u16*)(ws + 37748736);    // [4096][3072] bf16   25.17 MB
  u16*   attn  = (u16*)(ws + 62914560);    // [4096][2048] bf16   16.78 MB
  float* bcat  = (float*)(ws + 79691776);  // [3072] f32

  k_cast<<<4096, 256, 0, stream>>>(x, xb, 1048576);
  k_transpose_cast<<<dim3(32, 32), 256, 0, stream>>>(Wq, wqkvT, 2048, 2048);
  k_transpose_cast<<<dim3(8, 32), 256, 0, stream>>>(Wk, wqkvT + (size_t)2048 * 2048, 2048, 512);
  k_transpose_cast<<<dim3(8, 32), 256, 0, stream>>>(Wv, wqkvT + (size_t)2560 * 2048, 2048, 512);
  k_transpose_cast<<<dim3(32, 32), 256, 0, stream>>>(Wo, woT, 2048, 2048);
  k_concat_bias<<<12, 256, 0, stream>>>(bq, bk, bv, bcat);
  k_gemm<false><<<dim3(24, 32), 256, 0, stream>>>(xb, wqkvT, bcat, qkv, 4096, 3072, 2048);
  k_attn<<<dim3(32, 32, 2), 256, 0, stream>>>(qkv, attn);
  k_gemm<true><<<dim3(16, 32), 256, 0, stream>>>(attn, woT, bo, out, 4096, 2048, 2048);
}

// Round 5
// 290.076 us; speedup vs baseline: 1.6609x; 1.0632x over previous
//
#include <hip/hip_runtime.h>
#include <cstdint>
#include <cstddef>

typedef unsigned short u16;
typedef __bf16 bf16x8 __attribute__((ext_vector_type(8)));
typedef float f32x4 __attribute__((ext_vector_type(4)));
typedef unsigned short u16x4 __attribute__((ext_vector_type(4)));
typedef unsigned short u16x8 __attribute__((ext_vector_type(8)));
typedef uint32_t u32x4 __attribute__((ext_vector_type(4)));
typedef __attribute__((address_space(1))) unsigned int as1_uint;
typedef __attribute__((address_space(3))) unsigned int as3_uint;

__device__ __forceinline__ u16 f2bf(float f) {
  uint32_t u = __builtin_bit_cast(uint32_t, f);
  u += 0x7FFFu + ((u >> 16) & 1u);   // RNE to bf16
  return (u16)(u >> 16);
}

// one-instruction packed f32x2 -> bf16x2 (RNE), T12 recipe
__device__ __forceinline__ uint32_t cvtpk2bf(float a, float b) {
  uint32_t r;
  asm("v_cvt_pk_bf16_f32 %0, %1, %2" : "=v"(r) : "v"(a), "v"(b));
  return r;
}

__device__ __forceinline__ float max3f(float a, float b, float c) {
  return fmaxf(fmaxf(a, b), c);   // clang fuses to v_max3_f32
}

__device__ __forceinline__ void gld_lds16(const void* g, void* l) {
  __builtin_amdgcn_global_load_lds((as1_uint*)g, (as3_uint*)l, 16, 0, 0);
}

// ---------------- cast fp32 -> bf16, 8 elems/thread ----------------
__global__ __launch_bounds__(256) void k_cast(const float* __restrict__ in,
                                              u16* __restrict__ out, int n8) {
  int i = blockIdx.x * 256 + threadIdx.x;
  if (i >= n8) return;
  const float4* p = reinterpret_cast<const float4*>(in) + (size_t)i * 2;
  float4 a = p[0], b = p[1];
  u16x8 r;
  r[0] = f2bf(a.x); r[1] = f2bf(a.y); r[2] = f2bf(a.z); r[3] = f2bf(a.w);
  r[4] = f2bf(b.x); r[5] = f2bf(b.y); r[6] = f2bf(b.z); r[7] = f2bf(b.w);
  *reinterpret_cast<u16x8*>(out + (size_t)i * 8) = r;
}

// ---------------- W [K][N] f32  ->  Wt [N][K] bf16 ----------------
__global__ __launch_bounds__(256) void k_transpose_cast(const float* __restrict__ W,
                                                        u16* __restrict__ Wt,
                                                        int K, int N) {
  __shared__ u16 tile[64][72];
  int k0 = blockIdx.y * 64, n0 = blockIdx.x * 64;
  int r = threadIdx.x >> 4;
  int c4 = (threadIdx.x & 15) * 4;
#pragma unroll
  for (int i = 0; i < 4; ++i) {
    int kk = r + i * 16;
    float4 v = *reinterpret_cast<const float4*>(W + (size_t)(k0 + kk) * N + n0 + c4);
    tile[kk][c4 + 0] = f2bf(v.x); tile[kk][c4 + 1] = f2bf(v.y);
    tile[kk][c4 + 2] = f2bf(v.z); tile[kk][c4 + 3] = f2bf(v.w);
  }
  __syncthreads();
#pragma unroll
  for (int i = 0; i < 4; ++i) {
    int nn = r + i * 16;
    u16x4 o;
    o[0] = tile[c4 + 0][nn]; o[1] = tile[c4 + 1][nn];
    o[2] = tile[c4 + 2][nn]; o[3] = tile[c4 + 3][nn];
    *reinterpret_cast<u16x4*>(Wt + (size_t)(n0 + nn) * K + k0 + c4) = o;
  }
}

// ---------------- concat qkv bias ----------------
__global__ __launch_bounds__(256) void k_concat_bias(const float* __restrict__ bq,
                                                     const float* __restrict__ bk,
                                                     const float* __restrict__ bv,
                                                     float* __restrict__ out) {
  int i = blockIdx.x * 256 + threadIdx.x;
  if (i >= 3072) return;
  float v;
  if (i < 2048) v = bq[i];
  else if (i < 2560) v = bk[i - 2048];
  else v = bv[i - 2560];
  out[i] = v;
}

// ---------------- bf16 GEMM: C = A[M][K] @ Bt[N][K]^T + bias ----------------
// 128x128 tile, BK=64, 4 waves (2x2), 16x16x32 MFMA. (m97 structure)
template <bool F32OUT>
__global__ __launch_bounds__(256) void k_gemm(const u16* __restrict__ A,
                                              const u16* __restrict__ Bt,
                                              const float* __restrict__ bias,
                                              void* __restrict__ Cout,
                                              int M, int N, int K) {
  __shared__ __align__(16) u16 As[128 * 64];
  __shared__ __align__(16) u16 Bs[128 * 64];
  const int m0 = blockIdx.y * 128, n0 = blockIdx.x * 128;
  const int tid = threadIdx.x;
  const int l = tid & 63, w = tid >> 6;
  const int wm = w >> 1, wn = w & 1;
  const int lr = l & 15, lo = l >> 4;
  const int srow = w * 8 + (l >> 3);
  const int sc = (l & 7) ^ ((l >> 3) & 7);
  f32x4 acc[4][4] = {};
  for (int kt = 0; kt < K; kt += 64) {
    __syncthreads();
#pragma unroll
    for (int it = 0; it < 4; ++it) {
      int row = it * 32 + srow;
      gld_lds16(A + (size_t)(m0 + row) * K + kt + sc * 8,
                (char*)As + (it * 32 + w * 8) * 128);
      gld_lds16(Bt + (size_t)(n0 + row) * K + kt + sc * 8,
                (char*)Bs + (it * 32 + w * 8) * 128);
    }
    __syncthreads();
    bf16x8 af[4][2], bfr[4][2];
#pragma unroll
    for (int mi = 0; mi < 4; ++mi) {
      int row = wm * 64 + mi * 16 + lr;
#pragma unroll
      for (int ks = 0; ks < 2; ++ks) {
        int ch = (ks * 4 + lo) ^ (row & 7);
        af[mi][ks] = *reinterpret_cast<const bf16x8*>((const char*)As + row * 128 + ch * 16);
      }
    }
#pragma unroll
    for (int nj = 0; nj < 4; ++nj) {
      int row = wn * 64 + nj * 16 + lr;
#pragma unroll
      for (int ks = 0; ks < 2; ++ks) {
        int ch = (ks * 4 + lo) ^ (row & 7);
        bfr[nj][ks] = *reinterpret_cast<const bf16x8*>((const char*)Bs + row * 128 + ch * 16);
      }
    }
#pragma unroll
    for (int mi = 0; mi < 4; ++mi)
#pragma unroll
      for (int nj = 0; nj < 4; ++nj) {
        acc[mi][nj] = __builtin_amdgcn_mfma_f32_16x16x32_bf16(af[mi][0], bfr[nj][0], acc[mi][nj], 0, 0, 0);
        acc[mi][nj] = __builtin_amdgcn_mfma_f32_16x16x32_bf16(af[mi][1], bfr[nj][1], acc[mi][nj], 0, 0, 0);
      }
  }
#pragma unroll
  for (int mi = 0; mi < 4; ++mi) {
    int row = m0 + wm * 64 + mi * 16 + lo * 4;
#pragma unroll
    for (int nj = 0; nj < 4; ++nj) {
      int col = n0 + wn * 64 + nj * 16 + lr;
      float bv = bias[col];
#pragma unroll
      for (int r = 0; r < 4; ++r) {
        float v = acc[mi][nj][r] + bv;
        if (F32OUT) ((float*)Cout)[(size_t)(row + r) * N + col] = v;
        else        ((u16*)Cout)[(size_t)(row + r) * N + col] = f2bf(v);
      }
    }
  }
}

// ---------------- flash attention, swapped-QK^T + in-register P ----------------
// grid (S/64, NQ, B); 4 waves x 16 q-rows; KVBLK=64; HD=64.
// S^T = mfma(K,Q): lane(lo,lr) holds S[key=16t+4lo+r][q=lr]. Softmax lane-local.
// P pack via v_cvt_pk_bf16_f32; redistribute via permlane32/16_swap (no LDS).
// Defer-max THR=8 (T13): P bounded by 2^8, skip rescale while max growth < 8.
__global__ __launch_bounds__(256, 4) void k_attn(const u16* __restrict__ QKV,
                                                 u16* __restrict__ Oa) {
  constexpr int S = 2048, LDQ = 3072, LDV = 72;
  constexpr float THR = 8.0f;
  __shared__ __align__(16) u16 Ks[64 * 64];        // row-swizzled (chunk ^= row&7)
  __shared__ __align__(16) u16 Vt[64 * LDV];       // V^T [d][key]
  const int qt = blockIdx.x, h = blockIdx.y, b = blockIdx.z;
  const int kvh = h >> 2;
  const int tid = threadIdx.x, l = tid & 63, w = tid >> 6;
  const int lr = l & 15, lo = l >> 4;
  const size_t base = (size_t)b * S * LDQ;
  const u16* Qg = QKV + base + h * 64;
  const u16* Kg = QKV + base + 2048 + kvh * 64;
  const u16* Vg = QKV + base + 2560 + kvh * 64;
  const int qrow = qt * 64 + w * 16 + lr;
  const bf16x8 aq0 = *reinterpret_cast<const bf16x8*>(Qg + (size_t)qrow * LDQ + lo * 8);
  const bf16x8 aq1 = *reinterpret_cast<const bf16x8*>(Qg + (size_t)qrow * LDQ + 32 + lo * 8);
  const float SCL = 0.125f * 1.44269504088896341f;   // 1/sqrt(64) * log2(e)
  f32x4 acc[4] = {};
  float mrun = -1e30f, lsum = 0.f;
  const int krow = w * 8 + (l >> 3);
  const int ksc = (l & 7) ^ ((l >> 3) & 7);
  const int vkey = (l & 31) * 2;        // key pair owned by this lane
  const int vdh = (l >> 5) * 8;         // d-offset half within wave's 16 d-rows
  for (int kt = 0; kt < S; kt += 64) {
    __syncthreads();
    // K: 64x64 via global_load_lds (linear dest, pre-swizzled source chunk)
    gld_lds16(Kg + (size_t)(kt + krow) * LDQ + ksc * 8, (char*)Ks + (w * 8) * 128);
    gld_lds16(Kg + (size_t)(kt + 32 + krow) * LDQ + ksc * 8, (char*)Ks + (32 + w * 8) * 128);
    // V: lane owns keys (vkey, vkey+1) x 8 d-rows; packed b32 writes, conflict-free
    u16x8 va = *reinterpret_cast<const u16x8*>(Vg + (size_t)(kt + vkey) * LDQ + w * 16 + vdh);
    u16x8 vb = *reinterpret_cast<const u16x8*>(Vg + (size_t)(kt + vkey + 1) * LDQ + w * 16 + vdh);
#pragma unroll
    for (int j = 0; j < 8; ++j) {
      uint32_t pw = (uint32_t)va[j] | ((uint32_t)vb[j] << 16);
      *reinterpret_cast<uint32_t*>(&Vt[(w * 16 + vdh + j) * LDV + vkey]) = pw;
    }
    __syncthreads();
    // QK^T swapped: p[t*4+r] = S[key=16t+4lo+r][q=lr]
    float p[16];
    __builtin_amdgcn_s_setprio(1);
#pragma unroll
    for (int t = 0; t < 4; ++t) {
      const int row = t * 16 + lr;
      bf16x8 k0 = *reinterpret_cast<const bf16x8*>((const char*)Ks + row * 128 + ((lo ^ (row & 7)) * 16));
      bf16x8 k1 = *reinterpret_cast<const bf16x8*>((const char*)Ks + row * 128 + (((4 + lo) ^ (row & 7)) * 16));
      f32x4 zz = {};
      zz = __builtin_amdgcn_mfma_f32_16x16x32_bf16(k0, aq0, zz, 0, 0, 0);
      zz = __builtin_amdgcn_mfma_f32_16x16x32_bf16(k1, aq1, zz, 0, 0, 0);
#pragma unroll
      for (int r = 0; r < 4; ++r) p[t * 4 + r] = zz[r] * SCL;
    }
    __builtin_amdgcn_s_setprio(0);
    // tile max for q=lr: max3 tree (7x v_max3 + 1 max) + 2 shfl
    float m0 = max3f(p[0], p[1], p[2]);
    float m1 = max3f(p[3], p[4], p[5]);
    float m2 = max3f(p[6], p[7], p[8]);
    float m3 = max3f(p[9], p[10], p[11]);
    float m4 = max3f(p[12], p[13], p[14]);
    float tm = fmaxf(max3f(m0, m1, m2), max3f(m3, m4, p[15]));
    tm = fmaxf(tm, __shfl_xor(tm, 16, 64));
    tm = fmaxf(tm, __shfl_xor(tm, 32, 64));
    if (__all(tm <= mrun + THR)) {
      // defer-max: keep stale mrun; p bounded by 2^THR
#pragma unroll
      for (int i = 0; i < 16; ++i) p[i] = __builtin_amdgcn_exp2f(p[i] - mrun);
    } else {
      float mnew = fmaxf(mrun, tm);
      float alpha = __builtin_amdgcn_exp2f(mrun - mnew);
      mrun = mnew;
#pragma unroll
      for (int i = 0; i < 16; ++i) p[i] = __builtin_amdgcn_exp2f(p[i] - mnew);
      lsum *= alpha;
#pragma unroll
      for (int r = 0; r < 4; ++r) {
        float ar = __shfl(alpha, lo * 4 + r, 64);   // alpha for acc-row q=lo*4+r
#pragma unroll
        for (int nj = 0; nj < 4; ++nj) acc[nj][r] *= ar;
      }
    }
    float rs = (((p[0] + p[1]) + (p[2] + p[3])) + ((p[4] + p[5]) + (p[6] + p[7])))
             + (((p[8] + p[9]) + (p[10] + p[11])) + ((p[12] + p[13]) + (p[14] + p[15])));
    rs += __shfl_xor(rs, 16, 64);
    rs += __shfl_xor(rs, 32, 64);
    lsum += rs;
    // pack P pairs with v_cvt_pk_bf16_f32 (1 instr each)
    uint32_t w00 = cvtpk2bf(p[0], p[1]),   w01 = cvtpk2bf(p[2], p[3]);
    uint32_t w10 = cvtpk2bf(p[4], p[5]),   w11 = cvtpk2bf(p[6], p[7]);
    uint32_t w20 = cvtpk2bf(p[8], p[9]),   w21 = cvtpk2bf(p[10], p[11]);
    uint32_t w30 = cvtpk2bf(p[12], p[13]), w31 = cvtpk2bf(p[14], p[15]);
    // redistribute to A-frag layout: lane lo needs keys 8lo..8lo+7 (pa0), +32 (pa1)
    asm volatile("v_permlane32_swap_b32 %0, %1" : "+v"(w00), "+v"(w10));
    asm volatile("v_permlane16_swap_b32 %0, %1" : "+v"(w00), "+v"(w10));  // w00=d0 w10=d2
    asm volatile("v_permlane32_swap_b32 %0, %1" : "+v"(w01), "+v"(w11));
    asm volatile("v_permlane16_swap_b32 %0, %1" : "+v"(w01), "+v"(w11));  // w01=d1 w11=d3
    asm volatile("v_permlane32_swap_b32 %0, %1" : "+v"(w20), "+v"(w30));
    asm volatile("v_permlane16_swap_b32 %0, %1" : "+v"(w20), "+v"(w30));
    asm volatile("v_permlane32_swap_b32 %0, %1" : "+v"(w21), "+v"(w31));
    asm volatile("v_permlane16_swap_b32 %0, %1" : "+v"(w21), "+v"(w31));
    u32x4 pq0; pq0[0] = w00; pq0[1] = w01; pq0[2] = w10; pq0[3] = w11;
    u32x4 pq1; pq1[0] = w20; pq1[1] = w21; pq1[2] = w30; pq1[3] = w31;
    const bf16x8 pa0 = __builtin_bit_cast(bf16x8, pq0);
    const bf16x8 pa1 = __builtin_bit_cast(bf16x8, pq1);
    __builtin_amdgcn_s_setprio(1);
#pragma unroll
    for (int nj = 0; nj < 4; ++nj) {
      const bf16x8 bv0 = *reinterpret_cast<const bf16x8*>(&Vt[(nj * 16 + lr) * LDV + lo * 8]);
      const bf16x8 bv1 = *reinterpret_cast<const bf16x8*>(&Vt[(nj * 16 + lr) * LDV + 32 + lo * 8]);
      acc[nj] = __builtin_amdgcn_mfma_f32_16x16x32_bf16(pa0, bv0, acc[nj], 0, 0, 0);
      acc[nj] = __builtin_amdgcn_mfma_f32_16x16x32_bf16(pa1, bv1, acc[nj], 0, 0, 0);
    }
    __builtin_amdgcn_s_setprio(0);
  }
  float lf[4];
#pragma unroll
  for (int r = 0; r < 4; ++r) lf[r] = 1.0f / __shfl(lsum, lo * 4 + r, 64);
  const size_t orow = (size_t)b * S + qt * 64 + w * 16 + lo * 4;
#pragma unroll
  for (int nj = 0; nj < 4; ++nj) {
    const int col = h * 64 + nj * 16 + lr;
#pragma unroll
    for (int r = 0; r < 4; ++r)
      Oa[(orow + r) * 2048 + col] = f2bf(acc[nj][r] * lf[r]);
  }
}

// ---------------- host ----------------
extern "C" void kernel_launch(void* const* d_in, const int* in_sizes, int n_in,
                              void* d_out, int out_size, void* d_ws, size_t ws_size,
                              hipStream_t stream) {
  const float* x  = (const float*)d_in[0];
  const float* Wq = (const float*)d_in[1];
  const float* bq = (const float*)d_in[2];
  const float* Wk = (const float*)d_in[3];
  const float* bk = (const float*)d_in[4];
  const float* Wv = (const float*)d_in[5];
  const float* bv = (const float*)d_in[6];
  const float* Wo = (const float*)d_in[7];
  const float* bo = (const float*)d_in[8];
  float* out = (float*)d_out;
  char* ws = (char*)d_ws;

  u16*   xb    = (u16*)(ws + 0);           // [4096][2048] bf16   16.78 MB
  u16*   wqkvT = (u16*)(ws + 16777216);    // [3072][2048] bf16   12.58 MB
  u16*   woT   = (u16*)(ws + 29360128);    // [2048][2048] bf16    8.39 MB
  u16*   qkv   = (u16*)(ws + 37748736);    // [4096][3072] bf16   25.17 MB
  u16*   attn  = (u16*)(ws + 62914560);    // [4096][2048] bf16   16.78 MB
  float* bcat  = (float*)(ws + 79691776);  // [3072] f32

  k_cast<<<4096, 256, 0, stream>>>(x, xb, 1048576);
  k_transpose_cast<<<dim3(32, 32), 256, 0, stream>>>(Wq, wqkvT, 2048, 2048);
  k_transpose_cast<<<dim3(8, 32), 256, 0, stream>>>(Wk, wqkvT + (size_t)2048 * 2048, 2048, 512);
  k_transpose_cast<<<dim3(8, 32), 256, 0, stream>>>(Wv, wqkvT + (size_t)2560 * 2048, 2048, 512);
  k_transpose_cast<<<dim3(32, 32), 256, 0, stream>>>(Wo, woT, 2048, 2048);
  k_concat_bias<<<12, 256, 0, stream>>>(bq, bk, bv, bcat);
  k_gemm<false><<<dim3(24, 32), 256, 0, stream>>>(xb, wqkvT, bcat, qkv, 4096, 3072, 2048);
  k_attn<<<dim3(32, 32, 2), 256, 0, stream>>>(qkv, attn);
  k_gemm<true><<<dim3(16, 32), 256, 0, stream>>>(attn, woT, bo, out, 4096, 2048, 2048);
}